// Round 1
// baseline (495.981 us; speedup 1.0000x reference)
//
#include <hip/hip_runtime.h>
#include <cmath>

// ---------------------------------------------------------------------------
// NeighborAdjustingLoss: per-row top-k neighbor selection + masked normalize +
// softmax-weighted masked log-softmax loss, reduced to a scalar.
// B=4096 (sim is BxB), M=8192 (memory bank BxM), k=32, fp32.
// ---------------------------------------------------------------------------

__device__ inline float wave_max_f(float x) {
#pragma unroll
    for (int off = 32; off > 0; off >>= 1) x = fmaxf(x, __shfl_xor(x, off, 64));
    return x;
}
__device__ inline float wave_min_f(float x) {
#pragma unroll
    for (int off = 32; off > 0; off >>= 1) x = fminf(x, __shfl_xor(x, off, 64));
    return x;
}
__device__ inline float wave_sum_f(float x) {
#pragma unroll
    for (int off = 32; off > 0; off >>= 1) x += __shfl_xor(x, off, 64);
    return x;
}

// ---- centrality = row-mean of memory bank; also zero the output scalar ----
__global__ __launch_bounds__(256)
void cent_kernel(const float* __restrict__ mem, float* __restrict__ cent,
                 float* __restrict__ out, int M) {
    __shared__ float s[4];
    const int row = blockIdx.x;
    if (row == 0 && threadIdx.x == 0) out[0] = 0.0f;  // harness poisons d_out
    const float4* p = (const float4*)(mem + (size_t)row * M);
    const int n4 = M >> 2;
    float acc = 0.0f;
    for (int i = threadIdx.x; i < n4; i += 256) {
        float4 q = p[i];
        acc += (q.x + q.y) + (q.z + q.w);
    }
    acc = wave_sum_f(acc);
    const int lane = threadIdx.x & 63, wid = threadIdx.x >> 6;
    if (lane == 0) s[wid] = acc;
    __syncthreads();
    if (threadIdx.x == 0) cent[row] = (s[0] + s[1] + s[2] + s[3]) / (float)M;
}

// ---- per-row loss. One block (256 threads) per row. Requires B % 1024 == 0,
//      B/256 <= 16, k <= 64. (Instance: B=4096 -> 16 elems/thread, k=32.) ----
__global__ __launch_bounds__(256)
void row_loss_kernel(const float* __restrict__ sim,
                     const float* __restrict__ cent,
                     const int* __restrict__ knn,
                     const float* __restrict__ temp_p,
                     float* __restrict__ out, int B) {
    const int row = blockIdx.x;
    const int tid = threadIdx.x;
    const int lane = tid & 63;
    const int wid = tid >> 6;

    __shared__ float s_rv[8];
    __shared__ int   s_ri[4];
    __shared__ float s_nv[64];   // neighbor values
    __shared__ int   s_ni[64];   // neighbor indices

    const int   k    = knn[0];
    const float temp = temp_p[0];
    const int   C    = B >> 10;  // float4 chunks per thread (B/1024), =4

    // --- load row into registers (float4-coalesced); track off-diag min ---
    float v[16];
    const float4* rp = (const float4*)(sim + (size_t)row * B);
    float mnl = INFINITY;
    for (int c = 0; c < C; ++c) {
        float4 q = rp[c * 256 + tid];
        const int jb = (c * 256 + tid) << 2;
        float t[4] = {q.x, q.y, q.z, q.w};
#pragma unroll
        for (int m = 0; m < 4; ++m) {
            const bool diag = (jb + m == row);
            mnl = fminf(mnl, diag ? INFINITY : t[m]);
            v[c * 4 + m] = diag ? -INFINITY : t[m];
        }
    }

    // --- block min over off-diagonal -> mn_s ---
    float wm = wave_min_f(mnl);
    if (lane == 0) s_rv[wid] = wm;
    __syncthreads();
    float mn_s = fminf(fminf(s_rv[0], s_rv[1]), fminf(s_rv[2], s_rv[3]));
    __syncthreads();

    // --- k+1 block-argmax extractions: first k are neighbors, (k+1)th = mx_s ---
    float mx_s = 0.0f;
    for (int it = 0; it <= k; ++it) {
        float lv = -INFINITY;
        int   li = 0x7fffffff;
        for (int c = 0; c < C; ++c) {
#pragma unroll
            for (int m = 0; m < 4; ++m) {
                const float x = v[c * 4 + m];
                const int   j = ((c * 256 + tid) << 2) + m;
                if (x > lv || (x == lv && j < li)) { lv = x; li = j; }
            }
        }
#pragma unroll
        for (int off = 32; off > 0; off >>= 1) {
            const float ov = __shfl_down(lv, off, 64);
            const int   oi = __shfl_down(li, off, 64);
            if (ov > lv || (ov == lv && oi < li)) { lv = ov; li = oi; }
        }
        if (lane == 0) { s_rv[wid] = lv; s_ri[wid] = li; }
        __syncthreads();
        float bv = s_rv[0];
        int   bi = s_ri[0];
        for (int w = 1; w < 4; ++w) {
            const float wv = s_rv[w];
            const int   wi = s_ri[w];
            if (wv > bv || (wv == bv && wi < bi)) { bv = wv; bi = wi; }
        }
        __syncthreads();
        if (it < k) {
            if (tid == 0) { s_nv[it] = bv; s_ni[it] = bi; }
            const int q = bi >> 2;                 // owning float4 slot
            if ((q & 255) == tid) v[((q >> 8) << 2) + (bi & 3)] = -INFINITY;
        } else {
            mx_s = bv;  // 33rd largest off-diag value == max over mask==0
        }
    }
    __syncthreads();  // s_nv/s_ni visible to all

    // --- centrality min/max over columns not in {diag, neighbors} ---
    float cmin = INFINITY, cmax = -INFINITY;
    const float4* cp = (const float4*)cent;
    for (int c = 0; c < C; ++c) {
        float4 q = cp[c * 256 + tid];
        float t[4] = {q.x, q.y, q.z, q.w};
#pragma unroll
        for (int m = 0; m < 4; ++m) {
            if (v[c * 4 + m] != -INFINITY) {  // excluded slots were set to -inf
                cmin = fminf(cmin, t[m]);
                cmax = fmaxf(cmax, t[m]);
            }
        }
    }
    float wmn = wave_min_f(cmin);
    float wmx = wave_max_f(cmax);
    if (lane == 0) { s_rv[wid] = wmn; s_rv[4 + wid] = wmx; }
    __syncthreads();
    const float mn_c = fminf(fminf(s_rv[0], s_rv[1]), fminf(s_rv[2], s_rv[3]));
    const float mx_c = fmaxf(fmaxf(s_rv[4], s_rv[5]), fmaxf(s_rv[6], s_rv[7]));

    // --- finale on wave 0: softmax over k neighbors + masked log-softmax ---
    if (wid == 0) {
        const float sdiag = sim[(size_t)row * B + row];
        const bool  act = (lane < k);
        const float sj = act ? s_nv[lane] : -INFINITY;
        const int   j  = act ? s_ni[lane] : 0;
        const float cj = cent[j];

        float a = -INFINITY;
        if (act) {
            const float ns = (sj - mn_s) / (mx_s - mn_s);
            const float nc = (cj - mn_c) / (mx_c - mn_c);
            a = (ns - nc) * temp;
        }
        const float am   = wave_max_f(a);
        const float e    = act ? expf(a - am) : 0.0f;
        const float esum = wave_sum_f(e);
        const float pw   = e / esum;               // lanes >= k give 0

        const float m2  = fmaxf(wave_max_f(sj), sdiag);
        const float ex  = act ? expf(sj - m2) : 0.0f;
        const float lse = m2 + logf(wave_sum_f(ex) + expf(sdiag - m2));

        const float num = wave_sum_f(act ? pw * (sj - lse) : 0.0f) + (sdiag - lse);
        const float den = 1.0f + wave_sum_f(pw);
        if (lane == 0) atomicAdd(out, (-num / den) / (float)B);
    }
}

extern "C" void kernel_launch(void* const* d_in, const int* in_sizes, int n_in,
                              void* d_out, int out_size, void* d_ws, size_t ws_size,
                              hipStream_t stream) {
    const float* sim  = (const float*)d_in[0];
    const float* mem  = (const float*)d_in[1];
    const int*   knn  = (const int*)d_in[2];
    const float* temp = (const float*)d_in[3];
    float* out  = (float*)d_out;
    float* cent = (float*)d_ws;  // B floats of scratch

    const int B = (int)(std::sqrt((double)in_sizes[0]) + 0.5);
    const int M = in_sizes[1] / B;

    cent_kernel<<<B, 256, 0, stream>>>(mem, cent, out, M);
    row_loss_kernel<<<B, 256, 0, stream>>>(sim, cent, knn, temp, out, B);
}

// Round 2
// 295.824 us; speedup vs baseline: 1.6766x; 1.6766x over previous
//
#include <hip/hip_runtime.h>
#include <cmath>

// ---------------------------------------------------------------------------
// NeighborAdjustingLoss: per-row top-k via LDS histogram radix-select +
// masked normalize + softmax-weighted masked log-softmax loss -> scalar.
// B=4096 (sim BxB), M=8192 (mem BxM), k=32, fp32.
// ---------------------------------------------------------------------------

#define CAP 256   // candidate buffer entries (expected ~50 for N(0,1) rows)

__device__ inline float wave_max_f(float x) {
#pragma unroll
    for (int off = 32; off > 0; off >>= 1) x = fmaxf(x, __shfl_xor(x, off, 64));
    return x;
}
__device__ inline float wave_min_f(float x) {
#pragma unroll
    for (int off = 32; off > 0; off >>= 1) x = fminf(x, __shfl_xor(x, off, 64));
    return x;
}
__device__ inline float wave_sum_f(float x) {
#pragma unroll
    for (int off = 32; off > 0; off >>= 1) x += __shfl_xor(x, off, 64);
    return x;
}
__device__ inline unsigned int wave_min_u32(unsigned int x) {
#pragma unroll
    for (int off = 32; off > 0; off >>= 1) {
        unsigned int o = __shfl_xor((int)x, off, 64);
        x = (o < x) ? o : x;
    }
    return x;
}
__device__ inline unsigned int wave_max_u32(unsigned int x) {
#pragma unroll
    for (int off = 32; off > 0; off >>= 1) {
        unsigned int o = __shfl_xor((int)x, off, 64);
        x = (o > x) ? o : x;
    }
    return x;
}
__device__ inline unsigned long long wave_max_u64(unsigned long long x) {
#pragma unroll
    for (int off = 32; off > 0; off >>= 1) {
        unsigned long long o = __shfl_xor(x, off, 64);
        x = (o > x) ? o : x;
    }
    return x;
}

// order-preserving float<->uint key
__device__ inline unsigned int f_to_key(float f) {
    unsigned int u = __float_as_uint(f);
    return u ^ ((u & 0x80000000u) ? 0xFFFFFFFFu : 0x80000000u);
}
__device__ inline float key_to_f(unsigned int key) {
    unsigned int u = key ^ ((key & 0x80000000u) ? 0x80000000u : 0xFFFFFFFFu);
    return __uint_as_float(u);
}

// ---- centrality = row-mean of memory bank; also zero the output scalar ----
__global__ __launch_bounds__(256)
void cent_kernel(const float* __restrict__ mem, float* __restrict__ cent,
                 float* __restrict__ out, int M) {
    __shared__ float s[4];
    const int row = blockIdx.x;
    if (row == 0 && threadIdx.x == 0) out[0] = 0.0f;  // harness poisons d_out
    const float4* p = (const float4*)(mem + (size_t)row * M);
    const int n4 = M >> 2;
    float acc = 0.0f;
    for (int i = threadIdx.x; i < n4; i += 256) {
        float4 q = p[i];
        acc += (q.x + q.y) + (q.z + q.w);
    }
    acc = wave_sum_f(acc);
    const int lane = threadIdx.x & 63, wid = threadIdx.x >> 6;
    if (lane == 0) s[wid] = acc;
    __syncthreads();
    if (threadIdx.x == 0) cent[row] = (s[0] + s[1] + s[2] + s[3]) / (float)M;
}

// ---- per-row loss. One 256-thread block per row. Requires B==4096, k<=63. --
// Histogram bins = top-12 bits of the order key, stored bank-permuted:
//   bin b  ->  hist[(b >> 4) + ((b & 15) << 8)]
// so chunk-sum reads (thread t sums chunk t's 16 bins) are stride-256 words
// across lanes (conflict-free), while the per-element atomics stay random.
__global__ __launch_bounds__(256)
void row_loss_kernel(const float* __restrict__ sim,
                     const float* __restrict__ cent,
                     const int* __restrict__ knn,
                     const float* __restrict__ temp_p,
                     float* __restrict__ out, int B) {
    __shared__ unsigned int hist[4096];     // 16 KB, bank-permuted
    __shared__ unsigned int chunkS[256];
    __shared__ unsigned int candK[CAP];
    __shared__ int          candI[CAP];
    __shared__ unsigned int s_cnt, s_thr;
    __shared__ unsigned int s_kmin[4], s_kmax[4];
    __shared__ float        s_cmin[4], s_cmax[4];

    const int row  = blockIdx.x;
    const int tid  = threadIdx.x;
    const int lane = tid & 63;
    const int wid  = tid >> 6;
    const int   k    = knn[0];
    const float temp = temp_p[0];

    // --- zero histogram + counter ---
    {
        uint4 z = make_uint4(0, 0, 0, 0);
        uint4* h4 = (uint4*)hist;
#pragma unroll
        for (int i = 0; i < 4; ++i) h4[tid + 256 * i] = z;
        if (tid == 0) s_cnt = 0;
    }

    // --- load row (float4-coalesced), compute order keys; diag -> key 0 ---
    unsigned int keys[16];
    unsigned int kmin = 0xFFFFFFFFu, kmax = 0u;
    const float4* rp = (const float4*)(sim + (size_t)row * B);
#pragma unroll
    for (int c = 0; c < 4; ++c) {
        float4 q = rp[c * 256 + tid];
        float t[4] = {q.x, q.y, q.z, q.w};
#pragma unroll
        for (int m = 0; m < 4; ++m) {
            unsigned int key = f_to_key(t[m]);
            const bool diag = (c * 1024 + tid * 4 + m == row);
            key = diag ? 0u : key;
            keys[c * 4 + m] = key;
            kmin = (diag || key >= kmin) ? kmin : key;
            kmax = (key > kmax) ? key : kmax;
        }
    }
    __syncthreads();  // hist zero visible

    // --- histogram (skip diag) ---
#pragma unroll
    for (int i = 0; i < 16; ++i) {
        const unsigned int key = keys[i];
        if (key != 0u) {
            const unsigned int b = key >> 20;
            atomicAdd(&hist[(b >> 4) + ((b & 15u) << 8)], 1u);
        }
    }
    // block kmin/kmax (kmax is the scan-start hint)
    {
        unsigned int wmn = wave_min_u32(kmin), wmx = wave_max_u32(kmax);
        if (lane == 0) { s_kmin[wid] = wmn; s_kmax[wid] = wmx; }
    }
    __syncthreads();  // histogram + kmin/kmax visible

    // --- per-chunk sums (conflict-free: stride-256 words across lanes) ---
    {
        unsigned int S = 0;
#pragma unroll
        for (int i = 0; i < 16; ++i) S += hist[tid + (i << 8)];
        chunkS[tid] = S;
    }
    __syncthreads();

    // --- thread 0: find threshold bin containing the (k+1)-th largest ---
    if (tid == 0) {
        const unsigned int kmax_b =
            max(max(s_kmax[0], s_kmax[1]), max(s_kmax[2], s_kmax[3]));
        const unsigned int need = (unsigned int)k + 1u;
        int t = (int)(kmax_b >> 24);
        unsigned int acc = 0;
        while (t > 0) {
            const unsigned int s = chunkS[t];
            if (acc + s >= need) break;
            acc += s;
            --t;
        }
        int sub = 15;
        while (sub > 0) {
            acc += hist[t + (sub << 8)];
            if (acc >= need) break;
            --sub;
        }
        s_thr = ((unsigned int)(t * 16 + sub)) << 20;
    }
    __syncthreads();

    // --- gather candidates; centrality min/max over non-candidates ---
    const unsigned int thr = s_thr;
    float cmin = INFINITY, cmax = -INFINITY;
    const float4* cp = (const float4*)cent;
#pragma unroll
    for (int c = 0; c < 4; ++c) {
        float4 q = cp[c * 256 + tid];
        float t[4] = {q.x, q.y, q.z, q.w};
#pragma unroll
        for (int m = 0; m < 4; ++m) {
            const unsigned int key = keys[c * 4 + m];
            if (key == 0u) continue;  // diag: excluded everywhere
            if (key >= thr) {
                const unsigned int pos = atomicAdd(&s_cnt, 1u);
                if (pos < CAP) {
                    candK[pos] = key;
                    candI[pos] = c * 1024 + tid * 4 + m;
                }
            } else {
                cmin = fminf(cmin, t[m]);
                cmax = fmaxf(cmax, t[m]);
            }
        }
    }
    {
        float wmn = wave_min_f(cmin), wmx = wave_max_f(cmax);
        if (lane == 0) { s_cmin[wid] = wmn; s_cmax[wid] = wmx; }
    }
    __syncthreads();

    // --- wave 0: exact top-k over candidates + finale (no more barriers) ---
    if (wid == 0) {
        const int c = (int)min(s_cnt, (unsigned int)CAP);
        // packed = key:idx' so u64-max picks (value desc, index asc)
        unsigned long long p[CAP / 64];
#pragma unroll
        for (int s = 0; s < CAP / 64; ++s) {
            const int pos = lane + 64 * s;
            p[s] = (pos < c)
                 ? (((unsigned long long)candK[pos] << 32) |
                    (unsigned long long)(0xFFFFFFFFu - (unsigned int)candI[pos]))
                 : 0ull;
        }
        unsigned int nKey = 0u;
        int nIdx = 0;
        float mx_s = 0.0f;
        for (int r = 0; r <= k; ++r) {
            unsigned long long m = p[0];
#pragma unroll
            for (int s = 1; s < CAP / 64; ++s) m = (p[s] > m) ? p[s] : m;
            const unsigned long long w = wave_max_u64(m);
            if (r < k) {
                if (lane == r) {
                    nKey = (unsigned int)(w >> 32);
                    nIdx = (int)(0xFFFFFFFFu - (unsigned int)w);
                }
#pragma unroll
                for (int s = 0; s < CAP / 64; ++s)
                    if (p[s] == w) p[s] = 0ull;   // owner removes winner
            } else {
                mx_s = key_to_f((unsigned int)(w >> 32));  // (k+1)-th value
            }
        }
        // non-selected candidates still count for centrality min/max
        float cmin2 = INFINITY, cmax2 = -INFINITY;
#pragma unroll
        for (int s = 0; s < CAP / 64; ++s) {
            if (p[s] != 0ull) {
                const int j = (int)(0xFFFFFFFFu - (unsigned int)p[s]);
                const float cv = cent[j];
                cmin2 = fminf(cmin2, cv);
                cmax2 = fmaxf(cmax2, cv);
            }
        }
        cmin2 = wave_min_f(cmin2);
        cmax2 = wave_max_f(cmax2);
        const float mn_c = fminf(cmin2,
            fminf(fminf(s_cmin[0], s_cmin[1]), fminf(s_cmin[2], s_cmin[3])));
        const float mx_c = fmaxf(cmax2,
            fmaxf(fmaxf(s_cmax[0], s_cmax[1]), fmaxf(s_cmax[2], s_cmax[3])));
        const unsigned int kmin_b =
            min(min(s_kmin[0], s_kmin[1]), min(s_kmin[2], s_kmin[3]));
        const float mn_s = key_to_f(kmin_b);

        // --- finale (bit-identical math to validated round-1 kernel) ---
        const float sdiag = sim[(size_t)row * B + row];
        const bool  act = (lane < k);
        const float sj = act ? key_to_f(nKey) : -INFINITY;
        const int   j  = act ? nIdx : 0;
        const float cj = cent[j];

        float a = -INFINITY;
        if (act) {
            const float ns = (sj - mn_s) / (mx_s - mn_s);
            const float nc = (cj - mn_c) / (mx_c - mn_c);
            a = (ns - nc) * temp;
        }
        const float am   = wave_max_f(a);
        const float e    = act ? expf(a - am) : 0.0f;
        const float esum = wave_sum_f(e);
        const float pw   = e / esum;

        const float m2  = fmaxf(wave_max_f(sj), sdiag);
        const float ex  = act ? expf(sj - m2) : 0.0f;
        const float lse = m2 + logf(wave_sum_f(ex) + expf(sdiag - m2));

        const float num = wave_sum_f(act ? pw * (sj - lse) : 0.0f) + (sdiag - lse);
        const float den = 1.0f + wave_sum_f(pw);
        if (lane == 0) atomicAdd(out, (-num / den) / (float)B);
    }
}

extern "C" void kernel_launch(void* const* d_in, const int* in_sizes, int n_in,
                              void* d_out, int out_size, void* d_ws, size_t ws_size,
                              hipStream_t stream) {
    const float* sim  = (const float*)d_in[0];
    const float* mem  = (const float*)d_in[1];
    const int*   knn  = (const int*)d_in[2];
    const float* temp = (const float*)d_in[3];
    float* out  = (float*)d_out;
    float* cent = (float*)d_ws;  // B floats of scratch

    const int B = (int)(std::sqrt((double)in_sizes[0]) + 0.5);
    const int M = in_sizes[1] / B;

    cent_kernel<<<B, 256, 0, stream>>>(mem, cent, out, M);
    row_loss_kernel<<<B, 256, 0, stream>>>(sim, cent, knn, temp, out, B);
}

// Round 3
// 275.095 us; speedup vs baseline: 1.8029x; 1.0754x over previous
//
#include <hip/hip_runtime.h>
#include <cmath>

// ---------------------------------------------------------------------------
// NeighborAdjustingLoss: per-row top-k via adaptive-threshold candidate select
// (VALU counting + all-pairs exact rank on wave 0) + masked normalize +
// softmax-weighted masked log-softmax loss -> scalar.
// B=4096 (sim BxB), M=8192 (mem BxM), k=32, fp32.
// ---------------------------------------------------------------------------

#define CAP 512    // candidate capacity (expected ~93 for N(0,1) rows)
#define MAXIT 36   // u32-key bisection bound (1 iteration in practice)

__device__ inline float wave_max_f(float x) {
#pragma unroll
    for (int off = 32; off > 0; off >>= 1) x = fmaxf(x, __shfl_xor(x, off, 64));
    return x;
}
__device__ inline float wave_min_f(float x) {
#pragma unroll
    for (int off = 32; off > 0; off >>= 1) x = fminf(x, __shfl_xor(x, off, 64));
    return x;
}
__device__ inline float wave_sum_f(float x) {
#pragma unroll
    for (int off = 32; off > 0; off >>= 1) x += __shfl_xor(x, off, 64);
    return x;
}
__device__ inline unsigned int wave_min_u32(unsigned int x) {
#pragma unroll
    for (int off = 32; off > 0; off >>= 1) {
        unsigned int o = (unsigned int)__shfl_xor((int)x, off, 64);
        x = (o < x) ? o : x;
    }
    return x;
}
__device__ inline unsigned int wave_sum_u32(unsigned int x) {
#pragma unroll
    for (int off = 32; off > 0; off >>= 1) x += (unsigned int)__shfl_xor((int)x, off, 64);
    return x;
}

// order-preserving float<->uint key
__device__ inline unsigned int f_to_key(float f) {
    unsigned int u = __float_as_uint(f);
    return u ^ ((u & 0x80000000u) ? 0xFFFFFFFFu : 0x80000000u);
}
__device__ inline float key_to_f(unsigned int key) {
    unsigned int u = key ^ ((key & 0x80000000u) ? 0x80000000u : 0xFFFFFFFFu);
    return __uint_as_float(u);
}

// ---- centrality = row-mean of memory bank (8 loads in flight) ----
__global__ __launch_bounds__(256)
void cent_kernel(const float* __restrict__ mem, float* __restrict__ cent, int M) {
    __shared__ float s[4];
    const int row = blockIdx.x;
    const float4* p = (const float4*)(mem + (size_t)row * M);
    const int n4 = M >> 2;
    float acc = 0.0f;
    int i = threadIdx.x;
    for (; i + 1792 < n4; i += 2048) {
        float4 q0 = p[i], q1 = p[i + 256], q2 = p[i + 512], q3 = p[i + 768];
        float4 q4 = p[i + 1024], q5 = p[i + 1280], q6 = p[i + 1536], q7 = p[i + 1792];
        acc += ((q0.x + q0.y) + (q0.z + q0.w)) + ((q1.x + q1.y) + (q1.z + q1.w))
             + ((q2.x + q2.y) + (q2.z + q2.w)) + ((q3.x + q3.y) + (q3.z + q3.w))
             + ((q4.x + q4.y) + (q4.z + q4.w)) + ((q5.x + q5.y) + (q5.z + q5.w))
             + ((q6.x + q6.y) + (q6.z + q6.w)) + ((q7.x + q7.y) + (q7.z + q7.w));
    }
    for (; i < n4; i += 256) {
        float4 q = p[i];
        acc += (q.x + q.y) + (q.z + q.w);
    }
    acc = wave_sum_f(acc);
    const int lane = threadIdx.x & 63, wid = threadIdx.x >> 6;
    if (lane == 0) s[wid] = acc;
    __syncthreads();
    if (threadIdx.x == 0) cent[row] = (s[0] + s[1] + s[2] + s[3]) / (float)M;
}

// ---- per-row loss -> per_row[row]. One 256-thread block per row.
//      Requires B==4096, k<=63. ----
__global__ __launch_bounds__(256)
void row_loss_kernel(const float* __restrict__ sim,
                     const float* __restrict__ cent,
                     const int* __restrict__ knn,
                     const float* __restrict__ temp_p,
                     float* __restrict__ per_row, int B) {
    __shared__ __align__(16) unsigned long long cand[CAP];
    __shared__ unsigned long long s_sel[64];
    __shared__ unsigned long long s_p33;
    __shared__ unsigned int s_red[4];
    __shared__ unsigned int s_kmin[4];
    __shared__ float s_cmin[4], s_cmax[4];
    __shared__ unsigned int s_cnt;
    __shared__ float s_diag;

    const int row = blockIdx.x, tid = threadIdx.x;
    const int lane = tid & 63, wid = tid >> 6;
    const int   k    = knn[0];
    const float temp = temp_p[0];

    // --- load row (float4-coalesced), order keys; diag -> key 0 ---
    unsigned int keys[16];
    unsigned int kmin = 0xFFFFFFFFu;
    const float4* rp = (const float4*)(sim + (size_t)row * B);
#pragma unroll
    for (int c = 0; c < 4; ++c) {
        float4 q = rp[c * 256 + tid];
        float t[4] = {q.x, q.y, q.z, q.w};
#pragma unroll
        for (int m = 0; m < 4; ++m) {
            const int j = c * 1024 + tid * 4 + m;
            unsigned int key = f_to_key(t[m]);
            if (j == row) { s_diag = t[m]; key = 0u; }
            else if (key < kmin) kmin = key;
            keys[c * 4 + m] = key;
        }
    }
    { unsigned int w = wave_min_u32(kmin); if (lane == 0) s_kmin[wid] = w; }
    if (tid == 0) { s_cnt = 0; s_p33 = ((unsigned long long)1u) << 32; }

    // --- adaptive threshold: find keyT with count(key > keyT) in [k+1, CAP].
    //     First guess 2.0 hits [33,512] with huge margin for N(0,1) rows ->
    //     1 iteration; u32-key bisection guarantees exactness otherwise. ---
    unsigned int keyT = f_to_key(2.0f), loK = 0u, hiK = 0xFFFFFFFFu, cnt = 0;
    const unsigned int need = (unsigned int)k + 1u;
    for (int it = 0; it < MAXIT; ++it) {
        unsigned int cl = 0;
#pragma unroll
        for (int i = 0; i < 16; ++i) cl += (keys[i] > keyT) ? 1u : 0u;
        unsigned int ws = wave_sum_u32(cl);
        __syncthreads();                    // protect s_red reuse
        if (lane == 0) s_red[wid] = ws;
        __syncthreads();
        cnt = s_red[0] + s_red[1] + s_red[2] + s_red[3];
        if (cnt >= need && cnt <= CAP) break;
        if (cnt < need) { hiK = keyT; keyT = loK + ((keyT - loK) >> 1); }
        else            { loK = keyT; keyT = keyT + ((hiK - keyT) >> 1); }
    }

    // --- gather candidates (packed key:~idx); cent min/max over the rest ---
    float cmin = INFINITY, cmax = -INFINITY;
    const float4* cp = (const float4*)cent;
#pragma unroll
    for (int c = 0; c < 4; ++c) {
        float4 q = cp[c * 256 + tid];
        float t[4] = {q.x, q.y, q.z, q.w};
#pragma unroll
        for (int m = 0; m < 4; ++m) {
            const unsigned int key = keys[c * 4 + m];
            if (key == 0u) continue;        // diag: excluded everywhere
            if (key > keyT) {
                const unsigned int pos = atomicAdd(&s_cnt, 1u);
                if (pos < CAP)
                    cand[pos] = ((unsigned long long)key << 32) |
                                (unsigned long long)(0xFFFFFFFFu -
                                    (unsigned int)(c * 1024 + tid * 4 + m));
            } else {
                cmin = fminf(cmin, t[m]);
                cmax = fmaxf(cmax, t[m]);
            }
        }
    }
    { float a = wave_min_f(cmin), b = wave_max_f(cmax);
      if (lane == 0) { s_cmin[wid] = a; s_cmax[wid] = b; } }
    __syncthreads();

    // --- wave 0: exact all-pairs ranks over candidates + finale ---
    if (wid == 0) {
        const unsigned int n = min(s_cnt, (unsigned int)CAP);
        const int S = (int)((n + 63u) >> 6);
        unsigned long long own[CAP / 64];
        unsigned int rank[CAP / 64];
#pragma unroll
        for (int s = 0; s < CAP / 64; ++s) { own[s] = 0ull; rank[s] = 0u; }
        for (int s = 0; s < S; ++s) {
            const unsigned int pos = lane + 64u * s;
            if (pos < n) own[s] = cand[pos];
        }
        // broadcast b128 reads (conflict-free); rank = #{others > own}
        const ulonglong2* c2 = (const ulonglong2*)cand;
        const unsigned int np = n >> 1;
        for (unsigned int o = 0; o < np; ++o) {
            ulonglong2 pr = c2[o];
            for (int s = 0; s < S; ++s) {
                rank[s] += (pr.x > own[s]) ? 1u : 0u;
                rank[s] += (pr.y > own[s]) ? 1u : 0u;
            }
        }
        if (n & 1u) {
            unsigned long long x = cand[n - 1u];
            for (int s = 0; s < S; ++s) rank[s] += (x > own[s]) ? 1u : 0u;
        }
        // selected: rank < k; rank == k is the (k+1)-th largest (mx_s);
        // rank >= k candidates re-enter centrality min/max
        float cmin2 = INFINITY, cmax2 = -INFINITY;
        for (int s = 0; s < S; ++s) {
            const unsigned int pos = lane + 64u * s;
            if (pos < n) {
                const unsigned int r = rank[s];
                if (r < (unsigned int)k) s_sel[r] = own[s];
                else if (r == (unsigned int)k) s_p33 = own[s];
                if (r >= (unsigned int)k) {
                    const int j = (int)(0xFFFFFFFFu - (unsigned int)own[s]);
                    const float cv = cent[j];
                    cmin2 = fminf(cmin2, cv);
                    cmax2 = fmaxf(cmax2, cv);
                }
            }
        }
        __builtin_amdgcn_wave_barrier();   // order s_sel/s_p33 writes vs reads
        cmin2 = wave_min_f(cmin2);
        cmax2 = wave_max_f(cmax2);
        const float mn_c = fminf(cmin2,
            fminf(fminf(s_cmin[0], s_cmin[1]), fminf(s_cmin[2], s_cmin[3])));
        const float mx_c = fmaxf(cmax2,
            fmaxf(fmaxf(s_cmax[0], s_cmax[1]), fmaxf(s_cmax[2], s_cmax[3])));
        const unsigned int kminb =
            min(min(s_kmin[0], s_kmin[1]), min(s_kmin[2], s_kmin[3]));
        const float mn_s = key_to_f(kminb);
        const float mx_s = key_to_f((unsigned int)(s_p33 >> 32));

        // --- finale (math identical to validated round-1/2 kernels) ---
        const float sdiag = s_diag;
        const bool  act = (lane < k);
        const unsigned long long sel = act ? s_sel[lane] : 0ull;
        const float sj = act ? key_to_f((unsigned int)(sel >> 32)) : -INFINITY;
        const int   j  = act ? (int)(0xFFFFFFFFu - (unsigned int)sel) : 0;
        const float cj = cent[j];

        float a = -INFINITY;
        if (act) {
            const float ns = (sj - mn_s) / (mx_s - mn_s);
            const float nc = (cj - mn_c) / (mx_c - mn_c);
            a = (ns - nc) * temp;
        }
        const float am   = wave_max_f(a);
        const float e    = act ? expf(a - am) : 0.0f;
        const float esum = wave_sum_f(e);
        const float pw   = e / esum;

        const float m2  = fmaxf(wave_max_f(sj), sdiag);
        const float ex  = act ? expf(sj - m2) : 0.0f;
        const float lse = m2 + logf(wave_sum_f(ex) + expf(sdiag - m2));

        const float num = wave_sum_f(act ? pw * (sj - lse) : 0.0f) + (sdiag - lse);
        const float den = 1.0f + wave_sum_f(pw);
        if (lane == 0) per_row[row] = -num / den;
    }
}

// ---- final mean over per_row -> out[0] ----
__global__ __launch_bounds__(256)
void reduce_kernel(const float* __restrict__ per_row, float* __restrict__ out, int B) {
    __shared__ float s[4];
    float acc = 0.0f;
    const float4* p = (const float4*)per_row;
    const int n4 = B >> 2;
    for (int i = threadIdx.x; i < n4; i += 256) {
        float4 q = p[i];
        acc += (q.x + q.y) + (q.z + q.w);
    }
    acc = wave_sum_f(acc);
    const int lane = threadIdx.x & 63, wid = threadIdx.x >> 6;
    if (lane == 0) s[wid] = acc;
    __syncthreads();
    if (threadIdx.x == 0) out[0] = (s[0] + s[1] + s[2] + s[3]) / (float)B;
}

extern "C" void kernel_launch(void* const* d_in, const int* in_sizes, int n_in,
                              void* d_out, int out_size, void* d_ws, size_t ws_size,
                              hipStream_t stream) {
    const float* sim  = (const float*)d_in[0];
    const float* mem  = (const float*)d_in[1];
    const int*   knn  = (const int*)d_in[2];
    const float* temp = (const float*)d_in[3];
    float* out     = (float*)d_out;
    float* cent    = (float*)d_ws;                 // B floats
    float* per_row = (float*)d_ws + 4096;          // B floats

    const int B = (int)(std::sqrt((double)in_sizes[0]) + 0.5);
    const int M = in_sizes[1] / B;

    cent_kernel<<<B, 256, 0, stream>>>(mem, cent, M);
    row_loss_kernel<<<B, 256, 0, stream>>>(sim, cent, knn, temp, per_row, B);
    reduce_kernel<<<1, 256, 0, stream>>>(per_row, out, B);
}

// Round 4
// 249.212 us; speedup vs baseline: 1.9902x; 1.1039x over previous
//
#include <hip/hip_runtime.h>
#include <cmath>

// ---------------------------------------------------------------------------
// NeighborAdjustingLoss: per-row top-k via adaptive-threshold candidate select
// (single fused pass: count + gather + centrality min/max), exact all-pairs
// rank on wave 0 held entirely in VGPRs (no runtime-indexed private arrays ->
// no scratch), masked normalize + softmax-weighted masked log-softmax -> scalar.
// B=4096 (sim BxB), M=8192 (mem BxM), k=32, fp32.
// ---------------------------------------------------------------------------

#define CAP 256    // candidate capacity; expected ~93 for N(0,1) rows (>17 sigma)
#define MAXIT 40   // u32-key bisection bound (1 pass in practice)

__device__ inline float wave_max_f(float x) {
#pragma unroll
    for (int off = 32; off > 0; off >>= 1) x = fmaxf(x, __shfl_xor(x, off, 64));
    return x;
}
__device__ inline float wave_min_f(float x) {
#pragma unroll
    for (int off = 32; off > 0; off >>= 1) x = fminf(x, __shfl_xor(x, off, 64));
    return x;
}
__device__ inline float wave_sum_f(float x) {
#pragma unroll
    for (int off = 32; off > 0; off >>= 1) x += __shfl_xor(x, off, 64);
    return x;
}
__device__ inline unsigned int wave_min_u32(unsigned int x) {
#pragma unroll
    for (int off = 32; off > 0; off >>= 1) {
        unsigned int o = (unsigned int)__shfl_xor((int)x, off, 64);
        x = (o < x) ? o : x;
    }
    return x;
}

// order-preserving float<->uint key
__device__ inline unsigned int f_to_key(float f) {
    unsigned int u = __float_as_uint(f);
    return u ^ ((u & 0x80000000u) ? 0xFFFFFFFFu : 0x80000000u);
}
__device__ inline float key_to_f(unsigned int key) {
    unsigned int u = key ^ ((key & 0x80000000u) ? 0x80000000u : 0xFFFFFFFFu);
    return __uint_as_float(u);
}

// ---- centrality = row-mean of memory bank (8 loads in flight) ----
__global__ __launch_bounds__(256)
void cent_kernel(const float* __restrict__ mem, float* __restrict__ cent, int M) {
    __shared__ float s[4];
    const int row = blockIdx.x;
    const float4* p = (const float4*)(mem + (size_t)row * M);
    const int n4 = M >> 2;
    float acc = 0.0f;
    int i = threadIdx.x;
    for (; i + 1792 < n4; i += 2048) {
        float4 q0 = p[i], q1 = p[i + 256], q2 = p[i + 512], q3 = p[i + 768];
        float4 q4 = p[i + 1024], q5 = p[i + 1280], q6 = p[i + 1536], q7 = p[i + 1792];
        acc += ((q0.x + q0.y) + (q0.z + q0.w)) + ((q1.x + q1.y) + (q1.z + q1.w))
             + ((q2.x + q2.y) + (q2.z + q2.w)) + ((q3.x + q3.y) + (q3.z + q3.w))
             + ((q4.x + q4.y) + (q4.z + q4.w)) + ((q5.x + q5.y) + (q5.z + q5.w))
             + ((q6.x + q6.y) + (q6.z + q6.w)) + ((q7.x + q7.y) + (q7.z + q7.w));
    }
    for (; i < n4; i += 256) {
        float4 q = p[i];
        acc += (q.x + q.y) + (q.z + q.w);
    }
    acc = wave_sum_f(acc);
    const int lane = threadIdx.x & 63, wid = threadIdx.x >> 6;
    if (lane == 0) s[wid] = acc;
    __syncthreads();
    if (threadIdx.x == 0) cent[row] = (s[0] + s[1] + s[2] + s[3]) / (float)M;
}

// ---- per-row loss -> per_row[row]. One 256-thread block per row.
//      Requires B==4096, k<=63. ----
__global__ __launch_bounds__(256)
void row_loss_kernel(const float* __restrict__ sim,
                     const float* __restrict__ cent,
                     const int* __restrict__ knn,
                     const float* __restrict__ temp_p,
                     float* __restrict__ per_row, int B) {
    __shared__ __align__(16) unsigned long long cand[CAP];
    __shared__ unsigned long long s_sel[64];
    __shared__ unsigned long long s_p33;
    __shared__ unsigned int s_kmin[4];
    __shared__ float s_cmin[4], s_cmax[4];
    __shared__ unsigned int s_cnt;
    __shared__ float s_diag;

    const int row = blockIdx.x, tid = threadIdx.x;
    const int lane = tid & 63, wid = tid >> 6;
    const int   k    = knn[0];
    const float temp = temp_p[0];

    // --- load row (float4-coalesced), order keys; diag -> key 0 ---
    unsigned int keys[16];
    unsigned int kmin = 0xFFFFFFFFu;
    const float4* rp = (const float4*)(sim + (size_t)row * B);
#pragma unroll
    for (int c = 0; c < 4; ++c) {
        float4 q = rp[c * 256 + tid];
        float t[4] = {q.x, q.y, q.z, q.w};
#pragma unroll
        for (int m = 0; m < 4; ++m) {
            const int j = c * 1024 + tid * 4 + m;
            unsigned int key = f_to_key(t[m]);
            if (j == row) { s_diag = t[m]; key = 0u; }
            else if (key < kmin) kmin = key;
            keys[c * 4 + m] = key;
        }
    }
    { unsigned int w = wave_min_u32(kmin); if (lane == 0) s_kmin[wid] = w; }
    if (tid == 0) { s_cnt = 0; s_p33 = ((unsigned long long)1u) << 32; }

    // --- fused pass: gather candidates (key > keyT) + cent min/max over rest.
    //     First-guess threshold 2.0 puts count in [k+1, CAP] with huge margin
    //     for N(0,1) rows -> 1 pass; bisection fallback keeps it exact. ---
    unsigned int keyT = f_to_key(2.0f), loK = 0u, hiK = 0xFFFFFFFFu, cnt = 0;
    const unsigned int need = (unsigned int)k + 1u;
    float cmin, cmax;
    const float4* cp = (const float4*)cent;
    for (int it = 0; it < MAXIT; ++it) {
        cmin = INFINITY; cmax = -INFINITY;
        __syncthreads();                    // s_cnt (re)set visible
#pragma unroll
        for (int c = 0; c < 4; ++c) {
            float4 q = cp[c * 256 + tid];
            float t[4] = {q.x, q.y, q.z, q.w};
#pragma unroll
            for (int m = 0; m < 4; ++m) {
                const unsigned int key = keys[c * 4 + m];
                if (key == 0u) continue;    // diag: excluded everywhere
                if (key > keyT) {
                    const unsigned int pos = atomicAdd(&s_cnt, 1u);
                    if (pos < CAP)
                        cand[pos] = ((unsigned long long)key << 32) |
                                    (unsigned long long)(0xFFFFFFFFu -
                                        (unsigned int)(c * 1024 + tid * 4 + m));
                } else {
                    cmin = fminf(cmin, t[m]);
                    cmax = fmaxf(cmax, t[m]);
                }
            }
        }
        { float a = wave_min_f(cmin), b = wave_max_f(cmax);
          if (lane == 0) { s_cmin[wid] = a; s_cmax[wid] = b; } }
        __syncthreads();                    // cand/cnt/cmin/cmax visible
        cnt = s_cnt;
        if (cnt >= need && cnt <= CAP) break;
        if (cnt < need) { hiK = keyT; keyT = loK + ((keyT - loK) >> 1); }
        else            { loK = keyT; keyT = keyT + ((hiK - keyT) >> 1); }
        if (tid == 0) s_cnt = 0;
    }
    if (wid != 0) return;                   // waves 1-3 done

    // --- wave 0: exact all-pairs ranks, all state in named VGPRs ---
    {
        const unsigned int n = min(cnt, (unsigned int)CAP);
        const unsigned int p0 = lane, p1 = lane + 64u, p2 = lane + 128u, p3 = lane + 192u;
        unsigned long long own0 = 0ull, own1 = 0ull, own2 = 0ull, own3 = 0ull;
        if (p0 < n) own0 = cand[p0];
        if (p1 < n) own1 = cand[p1];
        if (p2 < n) own2 = cand[p2];
        if (p3 < n) own3 = cand[p3];
        unsigned int r0 = 0, r1 = 0, r2 = 0, r3 = 0;
        const ulonglong2* c2 = (const ulonglong2*)cand;   // broadcast b128 reads
        const unsigned int np = n >> 1;
        for (unsigned int o = 0; o < np; ++o) {
            ulonglong2 pr = c2[o];
            r0 += (pr.x > own0) ? 1u : 0u; r0 += (pr.y > own0) ? 1u : 0u;
            r1 += (pr.x > own1) ? 1u : 0u; r1 += (pr.y > own1) ? 1u : 0u;
            r2 += (pr.x > own2) ? 1u : 0u; r2 += (pr.y > own2) ? 1u : 0u;
            r3 += (pr.x > own3) ? 1u : 0u; r3 += (pr.y > own3) ? 1u : 0u;
        }
        if (n & 1u) {
            unsigned long long x = cand[n - 1u];
            r0 += (x > own0) ? 1u : 0u; r1 += (x > own1) ? 1u : 0u;
            r2 += (x > own2) ? 1u : 0u; r3 += (x > own3) ? 1u : 0u;
        }
        // selected: rank < k; rank == k is the (k+1)-th largest (mx_s);
        // rank >= k candidates re-enter centrality min/max
        float cmin2 = INFINITY, cmax2 = -INFINITY;
        const unsigned int uk = (unsigned int)k;
#define HANDLE(P, OWN, R)                                                     \
        if ((P) < n) {                                                        \
            if ((R) < uk) s_sel[R] = (OWN);                                   \
            else if ((R) == uk) s_p33 = (OWN);                                \
            if ((R) >= uk) {                                                  \
                const int jj = (int)(0xFFFFFFFFu - (unsigned int)(OWN));      \
                const float cv = cent[jj];                                    \
                cmin2 = fminf(cmin2, cv);                                     \
                cmax2 = fmaxf(cmax2, cv);                                     \
            }                                                                 \
        }
        HANDLE(p0, own0, r0)
        HANDLE(p1, own1, r1)
        HANDLE(p2, own2, r2)
        HANDLE(p3, own3, r3)
#undef HANDLE
        __builtin_amdgcn_wave_barrier();   // order s_sel/s_p33 writes vs reads
        cmin2 = wave_min_f(cmin2);
        cmax2 = wave_max_f(cmax2);
        const float mn_c = fminf(cmin2,
            fminf(fminf(s_cmin[0], s_cmin[1]), fminf(s_cmin[2], s_cmin[3])));
        const float mx_c = fmaxf(cmax2,
            fmaxf(fmaxf(s_cmax[0], s_cmax[1]), fmaxf(s_cmax[2], s_cmax[3])));
        const unsigned int kminb =
            min(min(s_kmin[0], s_kmin[1]), min(s_kmin[2], s_kmin[3]));
        const float mn_s = key_to_f(kminb);
        const float mx_s = key_to_f((unsigned int)(s_p33 >> 32));

        // --- finale (math identical to validated round-1/2/3 kernels) ---
        const float sdiag = s_diag;
        const bool  act = (lane < k);
        const unsigned long long sel = act ? s_sel[lane] : 0ull;
        const float sj = act ? key_to_f((unsigned int)(sel >> 32)) : -INFINITY;
        const int   j  = act ? (int)(0xFFFFFFFFu - (unsigned int)sel) : 0;
        const float cj = cent[j];

        float a = -INFINITY;
        if (act) {
            const float ns = (sj - mn_s) / (mx_s - mn_s);
            const float nc = (cj - mn_c) / (mx_c - mn_c);
            a = (ns - nc) * temp;
        }
        const float am   = wave_max_f(a);
        const float e    = act ? expf(a - am) : 0.0f;
        const float esum = wave_sum_f(e);
        const float pw   = e / esum;

        const float m2  = fmaxf(wave_max_f(sj), sdiag);
        const float ex  = act ? expf(sj - m2) : 0.0f;
        const float lse = m2 + logf(wave_sum_f(ex) + expf(sdiag - m2));

        const float num = wave_sum_f(act ? pw * (sj - lse) : 0.0f) + (sdiag - lse);
        const float den = 1.0f + wave_sum_f(pw);
        if (lane == 0) per_row[row] = -num / den;
    }
}

// ---- final mean over per_row -> out[0] ----
__global__ __launch_bounds__(256)
void reduce_kernel(const float* __restrict__ per_row, float* __restrict__ out, int B) {
    __shared__ float s[4];
    float acc = 0.0f;
    const float4* p = (const float4*)per_row;
    const int n4 = B >> 2;
    for (int i = threadIdx.x; i < n4; i += 256) {
        float4 q = p[i];
        acc += (q.x + q.y) + (q.z + q.w);
    }
    acc = wave_sum_f(acc);
    const int lane = threadIdx.x & 63, wid = threadIdx.x >> 6;
    if (lane == 0) s[wid] = acc;
    __syncthreads();
    if (threadIdx.x == 0) out[0] = (s[0] + s[1] + s[2] + s[3]) / (float)B;
}

extern "C" void kernel_launch(void* const* d_in, const int* in_sizes, int n_in,
                              void* d_out, int out_size, void* d_ws, size_t ws_size,
                              hipStream_t stream) {
    const float* sim  = (const float*)d_in[0];
    const float* mem  = (const float*)d_in[1];
    const int*   knn  = (const int*)d_in[2];
    const float* temp = (const float*)d_in[3];
    float* out     = (float*)d_out;
    float* cent    = (float*)d_ws;                 // B floats
    float* per_row = (float*)d_ws + 4096;          // B floats

    const int B = (int)(std::sqrt((double)in_sizes[0]) + 0.5);
    const int M = in_sizes[1] / B;

    cent_kernel<<<B, 256, 0, stream>>>(mem, cent, M);
    row_loss_kernel<<<B, 256, 0, stream>>>(sim, cent, knn, temp, per_row, B);
    reduce_kernel<<<1, 256, 0, stream>>>(per_row, out, B);
}